// Round 5
// baseline (741.777 us; speedup 1.0000x reference)
//
#include <hip/hip_runtime.h>

typedef unsigned short u16;
typedef __bf16 bf16x8 __attribute__((ext_vector_type(8)));
typedef unsigned short u16x8 __attribute__((ext_vector_type(8)));
typedef float f32x4 __attribute__((ext_vector_type(4)));

union V8 { u16x8 u; bf16x8 b; };

__device__ __forceinline__ u16 f2bf(float f) {
    unsigned u = __float_as_uint(f);
    u += 0x7fffu + ((u >> 16) & 1u);
    return (u16)(u >> 16);
}
__device__ __forceinline__ float bf2f(u16 h) {
    return __uint_as_float(((unsigned)h) << 16);
}

// tanh-approx gelu, divide-free: x * sigmoid(1.5957691*(x+0.044715x^3))
__device__ __forceinline__ float gelu_fast(float v) {
    const float p = v * fmaf(v * v, 0.044715f, 1.0f);
    const float t = fminf(1.5957691216057308f * p, 80.f);
    const float e = __expf(t);
    return v * e * __builtin_amdgcn_rcpf(e + 1.f);
}

// async global->LDS, 16B per lane. LDS dest = wave-uniform base + lane*16.
__device__ __forceinline__ void gld16(const void* g, void* l) {
    __builtin_amdgcn_global_load_lds(
        (const __attribute__((address_space(1))) void*)g,
        (__attribute__((address_space(3))) void*)l, 16, 0, 0);
}

// block-wide sum for blockDim.x == 256 (4 waves). Returns total to all threads.
__device__ __forceinline__ float block_sum256(float v, float* red) {
#pragma unroll
    for (int mk = 1; mk < 64; mk <<= 1) v += __shfl_xor(v, mk);
    __syncthreads();                  // protect red reuse across calls
    if ((threadIdx.x & 63) == 0) red[threadIdx.x >> 6] = v;
    __syncthreads();
    return red[0] + red[1] + red[2] + red[3];
}

// ---------------------------------------------------------------------------
// cond: cm[b][n] = sum_i silu(c[b][i]) * w_cond[i][n].  One block per 256
// cols handles ALL 8 batch rows -> w_cond read once (25 MB, not 8x).
__global__ __launch_bounds__(256)
void cond_kernel(const float* __restrict__ c, const float* __restrict__ w,
                 float* __restrict__ cm) {
    __shared__ float sc[8 * 1024];
    for (int i = threadIdx.x; i < 8192; i += 256) {
        float v = c[i];
        sc[i] = v / (1.f + expf(-v));
    }
    __syncthreads();
    const int col = blockIdx.x * 256 + threadIdx.x;
    float acc[8];
#pragma unroll
    for (int b = 0; b < 8; ++b) acc[b] = 0.f;
    for (int i = 0; i < 1024; ++i) {
        const float wv = w[(size_t)i * 6144 + col];
#pragma unroll
        for (int b = 0; b < 8; ++b) acc[b] = fmaf(sc[b * 1024 + i], wv, acc[b]);
    }
#pragma unroll
    for (int b = 0; b < 8; ++b) cm[b * 6144 + col] = acc[b];
}

// ---------------------------------------------------------------------------
// LayerNorm (stats fp32, output cast bf16) then modulate (bf16 semantics).
__global__ __launch_bounds__(256)
void ln_mod_kernel(const float* __restrict__ x, const float* __restrict__ cm,
                   int shift0, int scale0, u16* __restrict__ out) {
    __shared__ float red[8];
    const int row = blockIdx.x, tid = threadIdx.x;
    const int b = row >> 10;
    const float4 v = *(const float4*)(x + (size_t)row * 1024 + tid * 4);
    float s = v.x + v.y + v.z + v.w;
#pragma unroll
    for (int mk = 1; mk < 64; mk <<= 1) s += __shfl_xor(s, mk);
    if ((tid & 63) == 0) red[tid >> 6] = s;
    __syncthreads();
    const float mean = (red[0] + red[1] + red[2] + red[3]) * (1.f / 1024.f);
    const float d0 = v.x - mean, d1 = v.y - mean, d2 = v.z - mean, d3 = v.w - mean;
    float ss = d0 * d0 + d1 * d1 + d2 * d2 + d3 * d3;
#pragma unroll
    for (int mk = 1; mk < 64; mk <<= 1) ss += __shfl_xor(ss, mk);
    if ((tid & 63) == 0) red[4 + (tid >> 6)] = ss;
    __syncthreads();
    const float var = (red[4] + red[5] + red[6] + red[7]) * (1.f / 1024.f);
    const float rs = rsqrtf(var + 1e-6f);
    const float* cmb = cm + b * 6144;
    const int c0 = tid * 4;
    ushort4 ov;
    ov.x = f2bf(bf2f(f2bf(d0 * rs)) * cmb[scale0 + c0 + 0] + cmb[shift0 + c0 + 0]);
    ov.y = f2bf(bf2f(f2bf(d1 * rs)) * cmb[scale0 + c0 + 1] + cmb[shift0 + c0 + 1]);
    ov.z = f2bf(bf2f(f2bf(d2 * rs)) * cmb[scale0 + c0 + 2] + cmb[shift0 + c0 + 2]);
    ov.w = f2bf(bf2f(f2bf(d3 * rs)) * cmb[scale0 + c0 + 3] + cmb[shift0 + c0 + 3]);
    *(ushort4*)(out + (size_t)row * 1024 + c0) = ov;
}

// ---------------------------------------------------------------------------
// fp32 (R,C) -> bf16 transposed (C,R).  block (32,8), grid (C/32, R/32)
__global__ __launch_bounds__(256)
void transpose_cast(const float* __restrict__ in, u16* __restrict__ out,
                    int R, int C) {
    __shared__ float t[32][33];
    const int tx = threadIdx.x, ty = threadIdx.y;
    const int c0 = blockIdx.x * 32, r0 = blockIdx.y * 32;
#pragma unroll
    for (int i = 0; i < 4; ++i)
        t[ty + i * 8][tx] = in[(size_t)(r0 + ty + i * 8) * C + c0 + tx];
    __syncthreads();
#pragma unroll
    for (int i = 0; i < 4; ++i)
        out[(size_t)(c0 + ty + i * 8) * R + r0 + tx] = f2bf(t[tx][ty + i * 8]);
}

// ---------------------------------------------------------------------------
// V slice of kqv -> vT[bh][d][s]  (bf16). block (32,8), grid (32, 2, 128)
__global__ __launch_bounds__(256)
void vtrans_kernel(const u16* __restrict__ kqv, u16* __restrict__ vT) {
    __shared__ u16 t[32][33];
    const int tx = threadIdx.x, ty = threadIdx.y;
    const int s0 = blockIdx.x * 32, d0 = blockIdx.y * 32;
    const int bh = blockIdx.z, b = bh >> 4, h = bh & 15;
#pragma unroll
    for (int i = 0; i < 4; ++i) {
        int s = s0 + ty + i * 8;
        t[ty + i * 8][tx] = kqv[(size_t)(b * 1024 + s) * 3072 + 2048 + h * 64 + d0 + tx];
    }
    __syncthreads();
#pragma unroll
    for (int i = 0; i < 4; ++i) {
        int d = d0 + ty + i * 8;
        vT[((size_t)bh * 64 + d) * 1024 + s0 + tx] = t[tx][ty + i * 8];
    }
}

// ---------------------------------------------------------------------------
// GEMM  C[M][N] = A[M][K] (bf16) @ BT[N][K]^T (bf16), 128x128 tile, BK=32,
// global_load_lds staging, bank-swizzled LDS content (0 conflicts, R4),
// blockIdx.x = m_tile for XCD-local A reuse.
template <int EPI>
__global__ __launch_bounds__(256)
void gemm_epi(const u16* __restrict__ A, const u16* __restrict__ BT,
              int M, int N, int K,
              u16* __restrict__ outb, float* __restrict__ outf,
              const float* __restrict__ resid, const float* __restrict__ gatec,
              float* __restrict__ stats, int* __restrict__ counts) {
    __shared__ u16 As[128 * 32];
    __shared__ u16 Bs[128 * 32];
    __shared__ float red[4];
    __shared__ int ccnt[128];

    const int tid = threadIdx.x;
    const int lane = tid & 63;
    const int wave = tid >> 6;
    const int wm = wave & 1, wn = wave >> 1;
    const int quad = lane >> 4, l15 = lane & 15;
    const int tm = blockIdx.x * 128, tn = blockIdx.y * 128;

    const int srow = tid >> 2;                        // 0..63
    const int scol = (((tid & 3) ^ ((srow >> 1) & 3))) * 8;  // swizzled chunk
    const int rsw = (l15 >> 1) & 3;                   // frag-read swizzle

    // strength-reduced staging pointers (advance 32 elems per iter)
    const u16* pa = A + (size_t)(tm + srow) * K + scol;
    const u16* pb = BT + (size_t)(tn + srow) * K + scol;
    const size_t rstep = (size_t)64 * K;

    f32x4 acc[4][4];
#pragma unroll
    for (int i = 0; i < 4; ++i)
#pragma unroll
        for (int j = 0; j < 4; ++j) acc[i][j] = (f32x4){0.f, 0.f, 0.f, 0.f};

    for (int k0 = 0; k0 < K; k0 += 32) {
        __syncthreads();
        gld16(pa, As + wave * 512);
        gld16(pa + rstep, As + 2048 + wave * 512);
        gld16(pb, Bs + wave * 512);
        gld16(pb + rstep, Bs + 2048 + wave * 512);
        pa += 32; pb += 32;
        __syncthreads();
        V8 af[4], bfr[4];
#pragma unroll
        for (int i = 0; i < 4; ++i)
            af[i].u = *(const u16x8*)(As + (wm * 64 + i * 16 + l15) * 32 + ((quad ^ rsw) * 8));
#pragma unroll
        for (int j = 0; j < 4; ++j)
            bfr[j].u = *(const u16x8*)(Bs + (wn * 64 + j * 16 + l15) * 32 + ((quad ^ rsw) * 8));
#pragma unroll
        for (int i = 0; i < 4; ++i)
#pragma unroll
            for (int j = 0; j < 4; ++j)
                acc[i][j] = __builtin_amdgcn_mfma_f32_16x16x32_bf16(
                    af[i].b, bfr[j].b, acc[i][j], 0, 0, 0);
    }

    if (EPI == 2) {
        for (int i = tid; i < 128; i += 256) ccnt[i] = 0;
    }
    __syncthreads();

    // block-uniform batch index (128-row tiles never straddle a batch row)
    const int bb = tm >> 10;
    float gj[4];
    if (EPI == 1 || EPI == 3) {
#pragma unroll
        for (int j = 0; j < 4; ++j)
            gj[j] = gatec[bb * 6144 + tn + wn * 64 + j * 16 + l15];
    }

    float s0 = 0.f, s1 = 0.f, s2 = 0.f;
    int cj[4] = {0, 0, 0, 0};
#pragma unroll
    for (int i = 0; i < 4; ++i) {
#pragma unroll
        for (int j = 0; j < 4; ++j) {
#pragma unroll
            for (int r = 0; r < 4; ++r) {
                const int row = tm + wm * 64 + i * 16 + quad * 4 + r;
                const int col = tn + wn * 64 + j * 16 + l15;
                const float v = acc[i][j][r];
                const size_t idx = (size_t)row * N + col;
                if (EPI == 0) {
                    outb[idx] = f2bf(v);
                } else if (EPI == 1) {
                    const float xa = gj[j] * v;
                    const float xv = resid[idx];
                    const float o = xv + xa;
                    outf[idx] = o;
                    s0 += xa * xa; s1 += xv * xv; s2 += o * o;
                } else if (EPI == 2) {
                    cj[j] += (v > 0.f) ? 1 : 0;
                    s0 += v * v;
                    outb[idx] = f2bf(gelu_fast(v));
                } else {
                    const float xm = gj[j] * v;
                    const float o = resid[idx] + xm;
                    outf[idx] = o;
                    s0 += xm * xm;
                }
            }
        }
    }

    if (EPI == 1) {
        float t = block_sum256(s0, red); if (tid == 0) atomicAdd(&stats[0], t);
        t = block_sum256(s1, red);       if (tid == 0) atomicAdd(&stats[1], t);
        t = block_sum256(s2, red);       if (tid == 0) atomicAdd(&stats[2], t);
    } else if (EPI == 2) {
#pragma unroll
        for (int j = 0; j < 4; ++j) {
            int c = cj[j];
            c += __shfl_xor(c, 16);
            c += __shfl_xor(c, 32);
            if (quad == 0) atomicAdd(&ccnt[wn * 64 + j * 16 + l15], c);
        }
        __syncthreads();
        for (int i = tid; i < 128; i += 256) atomicAdd(&counts[tn + i], ccnt[i]);
        float t = block_sum256(s0, red); if (tid == 0) atomicAdd(&stats[3], t);
    } else if (EPI == 3) {
        float t = block_sum256(s0, red); if (tid == 0) atomicAdd(&stats[4], t);
    }
}

// ---------------------------------------------------------------------------
// Flash attention v3: keys split across waves, q-rows shared. (unchanged)
__global__ __launch_bounds__(256, 2)
void attn_kernel(const u16* __restrict__ kqv, const u16* __restrict__ vT,
                 u16* __restrict__ y, float* __restrict__ stats) {
    __shared__ __align__(16) char smem[49152];
    u16* Ks = (u16*)smem;              // 16 KB  [128 k][8 ch^(k&7)]
    u16* Vs = (u16*)(smem + 16384);    // 16 KB  [64 d][16 ch^(d&15)]
    u16* P  = (u16*)(smem + 32768);    // 16 KB  per-wave 4 KB [64 q][4 ch^fq]
    float* obuf = (float*)smem;                  // merge overlay: [64 q][72]
    float* mlb  = (float*)(smem + 32768);        // merge overlay: m/l [16][16]
    float* lbuf = (float*)(smem + 32768 + 2048); // merge overlay: 1/L per q

    const int tid = threadIdx.x, lane = tid & 63, w = tid >> 6;
    const int quad = lane >> 4, l15 = lane & 15;
    const int bh = blockIdx.y, b = bh >> 4, h = bh & 15;
    const int qbase = blockIdx.x * 64;
    const int fq = (l15 >> 1) & 3;

    V8 qf[4][2];
#pragma unroll
    for (int qt = 0; qt < 4; ++qt) {
        const size_t rq = ((size_t)(b * 1024 + qbase + qt * 16 + l15)) * 3072
                        + 1024 + h * 64 + quad * 8;
        qf[qt][0].u = *(const u16x8*)(kqv + rq);
        qf[qt][1].u = *(const u16x8*)(kqv + rq + 32);
    }

    float m[4], l[4];
    f32x4 o[4][4];
#pragma unroll
    for (int qt = 0; qt < 4; ++qt) { m[qt] = -__builtin_inff(); l[qt] = 0.f; }
#pragma unroll
    for (int dt = 0; dt < 4; ++dt)
#pragma unroll
        for (int qt = 0; qt < 4; ++qt) o[dt][qt] = (f32x4){0.f, 0.f, 0.f, 0.f};

    u16* wp = P + w * 2048;
    const size_t kbase = (size_t)(b * 1024) * 3072 + h * 64;
    const size_t vbase = (size_t)bh * 65536;

    for (int k0 = 0; k0 < 1024; k0 += 128) {
        __syncthreads();
#pragma unroll
        for (int i = 0; i < 4; ++i) {
            const int c = i * 256 + tid;
            {
                const int row = c >> 3, col8 = (c & 7) ^ (row & 7);
                gld16(kqv + kbase + (size_t)(k0 + row) * 3072 + col8 * 8,
                      Ks + (i * 256 + w * 64) * 8);
            }
            {
                const int d = c >> 4, col8 = (c & 15) ^ (d & 15);
                gld16(vT + vbase + (size_t)d * 1024 + k0 + col8 * 8,
                      Vs + (i * 256 + w * 64) * 8);
            }
        }
        __syncthreads();

        f32x4 s[2][4];
#pragma unroll
        for (int kt = 0; kt < 2; ++kt) {
            const int krow = w * 32 + kt * 16 + l15;
            V8 ak0, ak1;
            ak0.u = *(const u16x8*)(Ks + krow * 64 + ((quad ^ (l15 & 7)) * 8));
            ak1.u = *(const u16x8*)(Ks + krow * 64 + (((quad + 4) ^ (l15 & 7)) * 8));
#pragma unroll
            for (int qt = 0; qt < 4; ++qt) {
                s[kt][qt] = __builtin_amdgcn_mfma_f32_16x16x32_bf16(
                    ak0.b, qf[qt][0].b, (f32x4){0.f, 0.f, 0.f, 0.f}, 0, 0, 0);
                s[kt][qt] = __builtin_amdgcn_mfma_f32_16x16x32_bf16(
                    ak1.b, qf[qt][1].b, s[kt][qt], 0, 0, 0);
            }
        }

#pragma unroll
        for (int qt = 0; qt < 4; ++qt) {
            float mx = s[0][qt][0];
            mx = fmaxf(mx, s[0][qt][1]); mx = fmaxf(mx, s[0][qt][2]);
            mx = fmaxf(mx, s[0][qt][3]); mx = fmaxf(mx, s[1][qt][0]);
            mx = fmaxf(mx, s[1][qt][1]); mx = fmaxf(mx, s[1][qt][2]);
            mx = fmaxf(mx, s[1][qt][3]);
            mx *= 0.125f;
            mx = fmaxf(mx, __shfl_xor(mx, 16));
            mx = fmaxf(mx, __shfl_xor(mx, 32));
            const float mn = fmaxf(m[qt], mx);
            const float alpha = __expf(m[qt] - mn);
            float ps = 0.f;
            u16 pr[2][4];
#pragma unroll
            for (int kt = 0; kt < 2; ++kt)
#pragma unroll
                for (int r = 0; r < 4; ++r) {
                    const float p = __expf(s[kt][qt][r] * 0.125f - mn);
                    ps += p;
                    pr[kt][r] = f2bf(p);
                }
            ps += __shfl_xor(ps, 16);
            ps += __shfl_xor(ps, 32);
            l[qt] = l[qt] * alpha + ps;
            m[qt] = mn;
#pragma unroll
            for (int dt = 0; dt < 4; ++dt) o[dt][qt] *= alpha;
            const int qrow = qt * 16 + l15;
#pragma unroll
            for (int kt = 0; kt < 2; ++kt) {
                const int c0 = (kt * 2 + (quad >> 1)) ^ fq;
                u16* pdst = wp + qrow * 32 + c0 * 8 + (quad & 1) * 4;
                *(unsigned*)(pdst)     = (unsigned)pr[kt][0] | ((unsigned)pr[kt][1] << 16);
                *(unsigned*)(pdst + 2) = (unsigned)pr[kt][2] | ((unsigned)pr[kt][3] << 16);
            }
        }

        V8 pb[4];
#pragma unroll
        for (int qt = 0; qt < 4; ++qt)
            pb[qt].u = *(const u16x8*)(wp + (qt * 16 + l15) * 32 + ((quad ^ fq) * 8));
#pragma unroll
        for (int dt = 0; dt < 4; ++dt) {
            V8 av;
            av.u = *(const u16x8*)(Vs + (dt * 16 + l15) * 128 + (((w * 4 + quad) ^ l15) * 8));
#pragma unroll
            for (int qt = 0; qt < 4; ++qt)
                o[dt][qt] = __builtin_amdgcn_mfma_f32_16x16x32_bf16(
                    av.b, pb[qt].b, o[dt][qt], 0, 0, 0);
        }
    }

    __syncthreads();
    if (quad == 0) {
#pragma unroll
        for (int qt = 0; qt < 4; ++qt) {
            mlb[(w * 4 + qt) * 16 + l15] = m[qt];
            mlb[256 + (w * 4 + qt) * 16 + l15] = l[qt];
        }
    }
    __syncthreads();
    float scale[4];
#pragma unroll
    for (int qt = 0; qt < 4; ++qt) {
        float M = -__builtin_inff();
#pragma unroll
        for (int ww = 0; ww < 4; ++ww) M = fmaxf(M, mlb[(ww * 4 + qt) * 16 + l15]);
        float L = 0.f;
#pragma unroll
        for (int ww = 0; ww < 4; ++ww)
            L += mlb[256 + (ww * 4 + qt) * 16 + l15] *
                 __expf(mlb[(ww * 4 + qt) * 16 + l15] - M);
        scale[qt] = __expf(m[qt] - M);
        if (w == 0 && quad == 0) lbuf[qt * 16 + l15] = 1.f / L;
    }
    for (int ww = 0; ww < 4; ++ww) {
        if (ww == w) {
#pragma unroll
            for (int qt = 0; qt < 4; ++qt) {
                float* dst = obuf + (qt * 16 + l15) * 72 + quad * 4;
#pragma unroll
                for (int dt = 0; dt < 4; ++dt) {
                    f32x4 v = o[dt][qt] * scale[qt];
                    if (ww != 0) v += *(f32x4*)(dst + dt * 16);
                    *(f32x4*)(dst + dt * 16) = v;
                }
            }
        }
        __syncthreads();
    }
    if (w == 0) {
        float sv = lbuf[lane];
#pragma unroll
        for (int mk = 1; mk < 64; mk <<= 1) sv += __shfl_xor(sv, mk);
        if (lane == 0) atomicAdd(&stats[5], sv);
    }
    {
        const int q = tid >> 2, dseg = (tid & 3) * 16;
        const float il = lbuf[q];
        const float* src = obuf + q * 72 + dseg;
        __align__(16) u16 tmp[16];
#pragma unroll
        for (int j = 0; j < 16; ++j) tmp[j] = f2bf(src[j] * il);
        u16* ydst = y + ((size_t)(b * 1024 + qbase + q)) * 1024 + h * 64 + dseg;
        *(uint4*)(ydst) = *(uint4*)(tmp);
        *(uint4*)(ydst + 8) = *(uint4*)(tmp + 8);
    }
}

// ---------------------------------------------------------------------------
__global__ __launch_bounds__(256)
void finalize_kernel(const int* __restrict__ counts, const float* __restrict__ stats,
                     float* __restrict__ out7) {
    __shared__ float red[4];
    float d = 0.f, z = 0.f, pp = 0.f;
    for (int i = threadIdx.x; i < 4096; i += 256) {
        const int c = counts[i];
        const float frac = (float)c * (1.f / 8192.f);
        d += fabsf(frac - 0.5f);
        z += (c == 0) ? 1.f : 0.f;
        pp += (c == 8192) ? 1.f : 0.f;
    }
    d = block_sum256(d, red);
    z = block_sum256(z, red);
    pp = block_sum256(pp, red);
    if (threadIdx.x == 0) {
        out7[0] = d * (1.f / 4096.f);
        out7[1] = z * (1.f / 4096.f);
        out7[2] = pp * (1.f / 4096.f);
        out7[3] = stats[5] * (1.f / 131072.f);
        out7[4] = sqrtf(stats[0] / stats[1]);
        out7[5] = sqrtf(stats[4] / stats[2]);
        out7[6] = sqrtf(stats[3] / (8192.f * 4096.f));
    }
}

// ---------------------------------------------------------------------------
extern "C" void kernel_launch(void* const* d_in, const int* in_sizes, int n_in,
                              void* d_out, int out_size, void* d_ws, size_t ws_size,
                              hipStream_t stream) {
    const float* x      = (const float*)d_in[0];
    const float* c      = (const float*)d_in[1];
    const float* w_cond = (const float*)d_in[2];
    const float* w_qkv  = (const float*)d_in[3];
    const float* w_attn = (const float*)d_in[4];
    const float* w_mlp1 = (const float*)d_in[5];
    const float* w_mlp2 = (const float*)d_in[6];
    float* out = (float*)d_out;

    char* base = (char*)d_ws;
    size_t off = 0;
    auto alloc = [&](size_t n) { void* r = base + off; off += (n + 255) & ~(size_t)255; return r; };
    float* stats   = (float*)alloc(64);
    int*   counts  = (int*)alloc(4096 * 4);
    float* cm      = (float*)alloc((size_t)8 * 6144 * 4);
    u16*   x_mod   = (u16*)alloc((size_t)8192 * 1024 * 2);
    u16*   kqv     = (u16*)alloc((size_t)8192 * 3072 * 2);
    u16*   vT      = (u16*)alloc((size_t)128 * 64 * 1024 * 2);
    u16*   y       = (u16*)alloc((size_t)8192 * 1024 * 2);
    float* x1      = (float*)alloc((size_t)8192 * 1024 * 4);
    u16*   wt_qkv  = (u16*)alloc((size_t)3072 * 1024 * 2);
    u16*   wt_attn = (u16*)alloc((size_t)1024 * 1024 * 2);
    u16*   wt_mlp1 = (u16*)alloc((size_t)4096 * 1024 * 2);
    u16*   wt_mlp2 = (u16*)alloc((size_t)1024 * 4096 * 2);
    u16*   h_act   = kqv;
    u16*   x_mod2  = x_mod;
    (void)vT; (void)ws_size; (void)n_in; (void)in_sizes; (void)out_size;

    hipMemsetAsync(d_ws, 0, 256 + 4096 * 4, stream);

    dim3 tb(32, 8);
    transpose_cast<<<dim3(3072 / 32, 1024 / 32), tb, 0, stream>>>(w_qkv,  wt_qkv,  1024, 3072);
    transpose_cast<<<dim3(1024 / 32, 1024 / 32), tb, 0, stream>>>(w_attn, wt_attn, 1024, 1024);
    transpose_cast<<<dim3(4096 / 32, 1024 / 32), tb, 0, stream>>>(w_mlp1, wt_mlp1, 1024, 4096);
    transpose_cast<<<dim3(1024 / 32, 4096 / 32), tb, 0, stream>>>(w_mlp2, wt_mlp2, 4096, 1024);

    cond_kernel<<<24, 256, 0, stream>>>(c, w_cond, cm);

    ln_mod_kernel<<<8192, 256, 0, stream>>>(x, cm, 0, 1024, x_mod);

    // grid: (m_tiles, n_tiles) — blockIdx.x = m_tile for XCD locality
    gemm_epi<0><<<dim3(8192 / 128, 3072 / 128), 256, 0, stream>>>(
        x_mod, wt_qkv, 8192, 3072, 1024, kqv, nullptr, nullptr, nullptr, stats, nullptr);

    vtrans_kernel<<<dim3(32, 2, 128), tb, 0, stream>>>(kqv, vT);

    attn_kernel<<<dim3(16, 128), 256, 0, stream>>>(kqv, vT, y, stats);

    gemm_epi<1><<<dim3(8192 / 128, 1024 / 128), 256, 0, stream>>>(
        y, wt_attn, 8192, 1024, 1024, nullptr, x1, x, cm + 2 * 1024, stats, nullptr);

    ln_mod_kernel<<<8192, 256, 0, stream>>>(x1, cm, 3 * 1024, 4 * 1024, x_mod2);

    gemm_epi<2><<<dim3(8192 / 128, 4096 / 128), 256, 0, stream>>>(
        x_mod2, wt_mlp1, 8192, 4096, 1024, h_act, nullptr, nullptr, nullptr, stats, counts);

    gemm_epi<3><<<dim3(8192 / 128, 1024 / 128), 256, 0, stream>>>(
        h_act, wt_mlp2, 8192, 1024, 4096, nullptr, out, x1, cm + 5 * 1024, stats, nullptr);

    finalize_kernel<<<1, 256, 0, stream>>>(counts, stats, out + (size_t)8192 * 1024);
}

// Round 6
// 616.021 us; speedup vs baseline: 1.2041x; 1.2041x over previous
//
#include <hip/hip_runtime.h>

typedef unsigned short u16;
typedef __bf16 bf16x8 __attribute__((ext_vector_type(8)));
typedef unsigned short u16x8 __attribute__((ext_vector_type(8)));
typedef float f32x4 __attribute__((ext_vector_type(4)));

union V8 { u16x8 u; bf16x8 b; };

__device__ __forceinline__ u16 f2bf(float f) {
    unsigned u = __float_as_uint(f);
    u += 0x7fffu + ((u >> 16) & 1u);
    return (u16)(u >> 16);
}
__device__ __forceinline__ float bf2f(u16 h) {
    return __uint_as_float(((unsigned)h) << 16);
}

// tanh-approx gelu, divide-free: x * sigmoid(1.5957691*(x+0.044715x^3))
__device__ __forceinline__ float gelu_fast(float v) {
    const float p = v * fmaf(v * v, 0.044715f, 1.0f);
    const float t = fminf(1.5957691216057308f * p, 80.f);
    const float e = __expf(t);
    return v * e * __builtin_amdgcn_rcpf(e + 1.f);
}

// async global->LDS, 16B per lane. LDS dest = wave-uniform base + lane*16.
__device__ __forceinline__ void gld16(const void* g, void* l) {
    __builtin_amdgcn_global_load_lds(
        (const __attribute__((address_space(1))) void*)g,
        (__attribute__((address_space(3))) void*)l, 16, 0, 0);
}

// block-wide sum for blockDim.x == 256 (4 waves). Returns total to all threads.
__device__ __forceinline__ float block_sum256(float v, float* red) {
#pragma unroll
    for (int mk = 1; mk < 64; mk <<= 1) v += __shfl_xor(v, mk);
    __syncthreads();                  // protect red reuse across calls
    if ((threadIdx.x & 63) == 0) red[threadIdx.x >> 6] = v;
    __syncthreads();
    return red[0] + red[1] + red[2] + red[3];
}

// ---------------------------------------------------------------------------
// cond: cm[b][n] = sum_i silu(c[b][i]) * w_cond[i][n].
// Split-K: grid (24 col-tiles, 32 k-slices of 32 rows) = 768 blocks; w read
// exactly once; partials accumulated via fp32 atomicAdd into zeroed cm.
__global__ __launch_bounds__(256)
void cond_kernel(const float* __restrict__ c, const float* __restrict__ w,
                 float* __restrict__ cm) {
    __shared__ float sc[8 * 32];
    const int i0 = blockIdx.y * 32;
    for (int t = threadIdx.x; t < 256; t += 256) {
        const int bb = t >> 5, ii = t & 31;
        const float v = c[bb * 1024 + i0 + ii];
        sc[t] = v / (1.f + expf(-v));
    }
    __syncthreads();
    const int col = blockIdx.x * 256 + threadIdx.x;
    float acc[8];
#pragma unroll
    for (int b = 0; b < 8; ++b) acc[b] = 0.f;
    for (int i = 0; i < 32; ++i) {
        const float wv = w[(size_t)(i0 + i) * 6144 + col];
#pragma unroll
        for (int b = 0; b < 8; ++b) acc[b] = fmaf(sc[b * 32 + i], wv, acc[b]);
    }
#pragma unroll
    for (int b = 0; b < 8; ++b) atomicAdd(&cm[b * 6144 + col], acc[b]);
}

// ---------------------------------------------------------------------------
// LayerNorm (stats fp32, output cast bf16) then modulate (bf16 semantics).
__global__ __launch_bounds__(256)
void ln_mod_kernel(const float* __restrict__ x, const float* __restrict__ cm,
                   int shift0, int scale0, u16* __restrict__ out) {
    __shared__ float red[8];
    const int row = blockIdx.x, tid = threadIdx.x;
    const int b = row >> 10;
    const float4 v = *(const float4*)(x + (size_t)row * 1024 + tid * 4);
    float s = v.x + v.y + v.z + v.w;
#pragma unroll
    for (int mk = 1; mk < 64; mk <<= 1) s += __shfl_xor(s, mk);
    if ((tid & 63) == 0) red[tid >> 6] = s;
    __syncthreads();
    const float mean = (red[0] + red[1] + red[2] + red[3]) * (1.f / 1024.f);
    const float d0 = v.x - mean, d1 = v.y - mean, d2 = v.z - mean, d3 = v.w - mean;
    float ss = d0 * d0 + d1 * d1 + d2 * d2 + d3 * d3;
#pragma unroll
    for (int mk = 1; mk < 64; mk <<= 1) ss += __shfl_xor(ss, mk);
    if ((tid & 63) == 0) red[4 + (tid >> 6)] = ss;
    __syncthreads();
    const float var = (red[4] + red[5] + red[6] + red[7]) * (1.f / 1024.f);
    const float rs = rsqrtf(var + 1e-6f);
    const float* cmb = cm + b * 6144;
    const int c0 = tid * 4;
    ushort4 ov;
    ov.x = f2bf(bf2f(f2bf(d0 * rs)) * cmb[scale0 + c0 + 0] + cmb[shift0 + c0 + 0]);
    ov.y = f2bf(bf2f(f2bf(d1 * rs)) * cmb[scale0 + c0 + 1] + cmb[shift0 + c0 + 1]);
    ov.z = f2bf(bf2f(f2bf(d2 * rs)) * cmb[scale0 + c0 + 2] + cmb[shift0 + c0 + 2]);
    ov.w = f2bf(bf2f(f2bf(d3 * rs)) * cmb[scale0 + c0 + 3] + cmb[shift0 + c0 + 3]);
    *(ushort4*)(out + (size_t)row * 1024 + c0) = ov;
}

// ---------------------------------------------------------------------------
// fp32 (R,C) -> bf16 transposed (C,R).  block (32,8), grid (C/32, R/32)
__global__ __launch_bounds__(256)
void transpose_cast(const float* __restrict__ in, u16* __restrict__ out,
                    int R, int C) {
    __shared__ float t[32][33];
    const int tx = threadIdx.x, ty = threadIdx.y;
    const int c0 = blockIdx.x * 32, r0 = blockIdx.y * 32;
#pragma unroll
    for (int i = 0; i < 4; ++i)
        t[ty + i * 8][tx] = in[(size_t)(r0 + ty + i * 8) * C + c0 + tx];
    __syncthreads();
#pragma unroll
    for (int i = 0; i < 4; ++i)
        out[(size_t)(c0 + ty + i * 8) * R + r0 + tx] = f2bf(t[tx][ty + i * 8]);
}

// ---------------------------------------------------------------------------
// V slice of kqv -> vT[bh][d][s]  (bf16). block (32,8), grid (32, 2, 128)
__global__ __launch_bounds__(256)
void vtrans_kernel(const u16* __restrict__ kqv, u16* __restrict__ vT) {
    __shared__ u16 t[32][33];
    const int tx = threadIdx.x, ty = threadIdx.y;
    const int s0 = blockIdx.x * 32, d0 = blockIdx.y * 32;
    const int bh = blockIdx.z, b = bh >> 4, h = bh & 15;
#pragma unroll
    for (int i = 0; i < 4; ++i) {
        int s = s0 + ty + i * 8;
        t[ty + i * 8][tx] = kqv[(size_t)(b * 1024 + s) * 3072 + 2048 + h * 64 + d0 + tx];
    }
    __syncthreads();
#pragma unroll
    for (int i = 0; i < 4; ++i) {
        int d = d0 + ty + i * 8;
        vT[((size_t)bh * 64 + d) * 1024 + s0 + tx] = t[tx][ty + i * 8];
    }
}

// ---------------------------------------------------------------------------
// GEMM  C[M][N] = A[M][K] (bf16) @ BT[N][K]^T (bf16), 128x128 tile, BK=32,
// global_load_lds staging, bank-swizzled LDS content (0 conflicts, R4),
// blockIdx.x = m_tile for XCD-local A reuse.
template <int EPI>
__global__ __launch_bounds__(256)
void gemm_epi(const u16* __restrict__ A, const u16* __restrict__ BT,
              int M, int N, int K,
              u16* __restrict__ outb, float* __restrict__ outf,
              const float* __restrict__ resid, const float* __restrict__ gatec,
              float* __restrict__ stats, int* __restrict__ counts) {
    __shared__ u16 As[128 * 32];
    __shared__ u16 Bs[128 * 32];
    __shared__ float red[4];
    __shared__ int ccnt[128];

    const int tid = threadIdx.x;
    const int lane = tid & 63;
    const int wave = tid >> 6;
    const int wm = wave & 1, wn = wave >> 1;
    const int quad = lane >> 4, l15 = lane & 15;
    const int tm = blockIdx.x * 128, tn = blockIdx.y * 128;

    const int srow = tid >> 2;                        // 0..63
    const int scol = (((tid & 3) ^ ((srow >> 1) & 3))) * 8;  // swizzled chunk
    const int rsw = (l15 >> 1) & 3;                   // frag-read swizzle

    // strength-reduced staging pointers (advance 32 elems per iter)
    const u16* pa = A + (size_t)(tm + srow) * K + scol;
    const u16* pb = BT + (size_t)(tn + srow) * K + scol;
    const size_t rstep = (size_t)64 * K;

    f32x4 acc[4][4];
#pragma unroll
    for (int i = 0; i < 4; ++i)
#pragma unroll
        for (int j = 0; j < 4; ++j) acc[i][j] = (f32x4){0.f, 0.f, 0.f, 0.f};

    for (int k0 = 0; k0 < K; k0 += 32) {
        __syncthreads();
        gld16(pa, As + wave * 512);
        gld16(pa + rstep, As + 2048 + wave * 512);
        gld16(pb, Bs + wave * 512);
        gld16(pb + rstep, Bs + 2048 + wave * 512);
        pa += 32; pb += 32;
        __syncthreads();
        V8 af[4], bfr[4];
#pragma unroll
        for (int i = 0; i < 4; ++i)
            af[i].u = *(const u16x8*)(As + (wm * 64 + i * 16 + l15) * 32 + ((quad ^ rsw) * 8));
#pragma unroll
        for (int j = 0; j < 4; ++j)
            bfr[j].u = *(const u16x8*)(Bs + (wn * 64 + j * 16 + l15) * 32 + ((quad ^ rsw) * 8));
#pragma unroll
        for (int i = 0; i < 4; ++i)
#pragma unroll
            for (int j = 0; j < 4; ++j)
                acc[i][j] = __builtin_amdgcn_mfma_f32_16x16x32_bf16(
                    af[i].b, bfr[j].b, acc[i][j], 0, 0, 0);
    }

    if (EPI == 2) {
        for (int i = tid; i < 128; i += 256) ccnt[i] = 0;
    }
    __syncthreads();

    // block-uniform batch index (128-row tiles never straddle a batch row)
    const int bb = tm >> 10;
    float gj[4];
    if (EPI == 1 || EPI == 3) {
#pragma unroll
        for (int j = 0; j < 4; ++j)
            gj[j] = gatec[bb * 6144 + tn + wn * 64 + j * 16 + l15];
    }

    float s0 = 0.f, s1 = 0.f, s2 = 0.f;
    int cj[4] = {0, 0, 0, 0};
#pragma unroll
    for (int i = 0; i < 4; ++i) {
#pragma unroll
        for (int j = 0; j < 4; ++j) {
#pragma unroll
            for (int r = 0; r < 4; ++r) {
                const int row = tm + wm * 64 + i * 16 + quad * 4 + r;
                const int col = tn + wn * 64 + j * 16 + l15;
                const float v = acc[i][j][r];
                const size_t idx = (size_t)row * N + col;
                if (EPI == 0) {
                    outb[idx] = f2bf(v);
                } else if (EPI == 1) {
                    const float xa = gj[j] * v;
                    const float xv = resid[idx];
                    const float o = xv + xa;
                    outf[idx] = o;
                    s0 += xa * xa; s1 += xv * xv; s2 += o * o;
                } else if (EPI == 2) {
                    cj[j] += (v > 0.f) ? 1 : 0;
                    s0 += v * v;
                    outb[idx] = f2bf(gelu_fast(v));
                } else {
                    const float xm = gj[j] * v;
                    const float o = resid[idx] + xm;
                    outf[idx] = o;
                    s0 += xm * xm;
                }
            }
        }
    }

    if (EPI == 1) {
        float t = block_sum256(s0, red); if (tid == 0) atomicAdd(&stats[0], t);
        t = block_sum256(s1, red);       if (tid == 0) atomicAdd(&stats[1], t);
        t = block_sum256(s2, red);       if (tid == 0) atomicAdd(&stats[2], t);
    } else if (EPI == 2) {
#pragma unroll
        for (int j = 0; j < 4; ++j) {
            int c = cj[j];
            c += __shfl_xor(c, 16);
            c += __shfl_xor(c, 32);
            if (quad == 0) atomicAdd(&ccnt[wn * 64 + j * 16 + l15], c);
        }
        __syncthreads();
        for (int i = tid; i < 128; i += 256) atomicAdd(&counts[tn + i], ccnt[i]);
        float t = block_sum256(s0, red); if (tid == 0) atomicAdd(&stats[3], t);
    } else if (EPI == 3) {
        float t = block_sum256(s0, red); if (tid == 0) atomicAdd(&stats[4], t);
    }
}

// ---------------------------------------------------------------------------
// Flash attention v3: keys split across waves, q-rows shared. (unchanged)
__global__ __launch_bounds__(256, 2)
void attn_kernel(const u16* __restrict__ kqv, const u16* __restrict__ vT,
                 u16* __restrict__ y, float* __restrict__ stats) {
    __shared__ __align__(16) char smem[49152];
    u16* Ks = (u16*)smem;              // 16 KB  [128 k][8 ch^(k&7)]
    u16* Vs = (u16*)(smem + 16384);    // 16 KB  [64 d][16 ch^(d&15)]
    u16* P  = (u16*)(smem + 32768);    // 16 KB  per-wave 4 KB [64 q][4 ch^fq]
    float* obuf = (float*)smem;                  // merge overlay: [64 q][72]
    float* mlb  = (float*)(smem + 32768);        // merge overlay: m/l [16][16]
    float* lbuf = (float*)(smem + 32768 + 2048); // merge overlay: 1/L per q

    const int tid = threadIdx.x, lane = tid & 63, w = tid >> 6;
    const int quad = lane >> 4, l15 = lane & 15;
    const int bh = blockIdx.y, b = bh >> 4, h = bh & 15;
    const int qbase = blockIdx.x * 64;
    const int fq = (l15 >> 1) & 3;

    V8 qf[4][2];
#pragma unroll
    for (int qt = 0; qt < 4; ++qt) {
        const size_t rq = ((size_t)(b * 1024 + qbase + qt * 16 + l15)) * 3072
                        + 1024 + h * 64 + quad * 8;
        qf[qt][0].u = *(const u16x8*)(kqv + rq);
        qf[qt][1].u = *(const u16x8*)(kqv + rq + 32);
    }

    float m[4], l[4];
    f32x4 o[4][4];
#pragma unroll
    for (int qt = 0; qt < 4; ++qt) { m[qt] = -__builtin_inff(); l[qt] = 0.f; }
#pragma unroll
    for (int dt = 0; dt < 4; ++dt)
#pragma unroll
        for (int qt = 0; qt < 4; ++qt) o[dt][qt] = (f32x4){0.f, 0.f, 0.f, 0.f};

    u16* wp = P + w * 2048;
    const size_t kbase = (size_t)(b * 1024) * 3072 + h * 64;
    const size_t vbase = (size_t)bh * 65536;

    for (int k0 = 0; k0 < 1024; k0 += 128) {
        __syncthreads();
#pragma unroll
        for (int i = 0; i < 4; ++i) {
            const int c = i * 256 + tid;
            {
                const int row = c >> 3, col8 = (c & 7) ^ (row & 7);
                gld16(kqv + kbase + (size_t)(k0 + row) * 3072 + col8 * 8,
                      Ks + (i * 256 + w * 64) * 8);
            }
            {
                const int d = c >> 4, col8 = (c & 15) ^ (d & 15);
                gld16(vT + vbase + (size_t)d * 1024 + k0 + col8 * 8,
                      Vs + (i * 256 + w * 64) * 8);
            }
        }
        __syncthreads();

        f32x4 s[2][4];
#pragma unroll
        for (int kt = 0; kt < 2; ++kt) {
            const int krow = w * 32 + kt * 16 + l15;
            V8 ak0, ak1;
            ak0.u = *(const u16x8*)(Ks + krow * 64 + ((quad ^ (l15 & 7)) * 8));
            ak1.u = *(const u16x8*)(Ks + krow * 64 + (((quad + 4) ^ (l15 & 7)) * 8));
#pragma unroll
            for (int qt = 0; qt < 4; ++qt) {
                s[kt][qt] = __builtin_amdgcn_mfma_f32_16x16x32_bf16(
                    ak0.b, qf[qt][0].b, (f32x4){0.f, 0.f, 0.f, 0.f}, 0, 0, 0);
                s[kt][qt] = __builtin_amdgcn_mfma_f32_16x16x32_bf16(
                    ak1.b, qf[qt][1].b, s[kt][qt], 0, 0, 0);
            }
        }

#pragma unroll
        for (int qt = 0; qt < 4; ++qt) {
            float mx = s[0][qt][0];
            mx = fmaxf(mx, s[0][qt][1]); mx = fmaxf(mx, s[0][qt][2]);
            mx = fmaxf(mx, s[0][qt][3]); mx = fmaxf(mx, s[1][qt][0]);
            mx = fmaxf(mx, s[1][qt][1]); mx = fmaxf(mx, s[1][qt][2]);
            mx = fmaxf(mx, s[1][qt][3]);
            mx *= 0.125f;
            mx = fmaxf(mx, __shfl_xor(mx, 16));
            mx = fmaxf(mx, __shfl_xor(mx, 32));
            const float mn = fmaxf(m[qt], mx);
            const float alpha = __expf(m[qt] - mn);
            float ps = 0.f;
            u16 pr[2][4];
#pragma unroll
            for (int kt = 0; kt < 2; ++kt)
#pragma unroll
                for (int r = 0; r < 4; ++r) {
                    const float p = __expf(s[kt][qt][r] * 0.125f - mn);
                    ps += p;
                    pr[kt][r] = f2bf(p);
                }
            ps += __shfl_xor(ps, 16);
            ps += __shfl_xor(ps, 32);
            l[qt] = l[qt] * alpha + ps;
            m[qt] = mn;
#pragma unroll
            for (int dt = 0; dt < 4; ++dt) o[dt][qt] *= alpha;
            const int qrow = qt * 16 + l15;
#pragma unroll
            for (int kt = 0; kt < 2; ++kt) {
                const int c0 = (kt * 2 + (quad >> 1)) ^ fq;
                u16* pdst = wp + qrow * 32 + c0 * 8 + (quad & 1) * 4;
                *(unsigned*)(pdst)     = (unsigned)pr[kt][0] | ((unsigned)pr[kt][1] << 16);
                *(unsigned*)(pdst + 2) = (unsigned)pr[kt][2] | ((unsigned)pr[kt][3] << 16);
            }
        }

        V8 pb[4];
#pragma unroll
        for (int qt = 0; qt < 4; ++qt)
            pb[qt].u = *(const u16x8*)(wp + (qt * 16 + l15) * 32 + ((quad ^ fq) * 8));
#pragma unroll
        for (int dt = 0; dt < 4; ++dt) {
            V8 av;
            av.u = *(const u16x8*)(Vs + (dt * 16 + l15) * 128 + (((w * 4 + quad) ^ l15) * 8));
#pragma unroll
            for (int qt = 0; qt < 4; ++qt)
                o[dt][qt] = __builtin_amdgcn_mfma_f32_16x16x32_bf16(
                    av.b, pb[qt].b, o[dt][qt], 0, 0, 0);
        }
    }

    __syncthreads();
    if (quad == 0) {
#pragma unroll
        for (int qt = 0; qt < 4; ++qt) {
            mlb[(w * 4 + qt) * 16 + l15] = m[qt];
            mlb[256 + (w * 4 + qt) * 16 + l15] = l[qt];
        }
    }
    __syncthreads();
    float scale[4];
#pragma unroll
    for (int qt = 0; qt < 4; ++qt) {
        float M = -__builtin_inff();
#pragma unroll
        for (int ww = 0; ww < 4; ++ww) M = fmaxf(M, mlb[(ww * 4 + qt) * 16 + l15]);
        float L = 0.f;
#pragma unroll
        for (int ww = 0; ww < 4; ++ww)
            L += mlb[256 + (ww * 4 + qt) * 16 + l15] *
                 __expf(mlb[(ww * 4 + qt) * 16 + l15] - M);
        scale[qt] = __expf(m[qt] - M);
        if (w == 0 && quad == 0) lbuf[qt * 16 + l15] = 1.f / L;
    }
    for (int ww = 0; ww < 4; ++ww) {
        if (ww == w) {
#pragma unroll
            for (int qt = 0; qt < 4; ++qt) {
                float* dst = obuf + (qt * 16 + l15) * 72 + quad * 4;
#pragma unroll
                for (int dt = 0; dt < 4; ++dt) {
                    f32x4 v = o[dt][qt] * scale[qt];
                    if (ww != 0) v += *(f32x4*)(dst + dt * 16);
                    *(f32x4*)(dst + dt * 16) = v;
                }
            }
        }
        __syncthreads();
    }
    if (w == 0) {
        float sv = lbuf[lane];
#pragma unroll
        for (int mk = 1; mk < 64; mk <<= 1) sv += __shfl_xor(sv, mk);
        if (lane == 0) atomicAdd(&stats[5], sv);
    }
    {
        const int q = tid >> 2, dseg = (tid & 3) * 16;
        const float il = lbuf[q];
        const float* src = obuf + q * 72 + dseg;
        __align__(16) u16 tmp[16];
#pragma unroll
        for (int j = 0; j < 16; ++j) tmp[j] = f2bf(src[j] * il);
        u16* ydst = y + ((size_t)(b * 1024 + qbase + q)) * 1024 + h * 64 + dseg;
        *(uint4*)(ydst) = *(uint4*)(tmp);
        *(uint4*)(ydst + 8) = *(uint4*)(tmp + 8);
    }
}

// ---------------------------------------------------------------------------
__global__ __launch_bounds__(256)
void finalize_kernel(const int* __restrict__ counts, const float* __restrict__ stats,
                     float* __restrict__ out7) {
    __shared__ float red[4];
    float d = 0.f, z = 0.f, pp = 0.f;
    for (int i = threadIdx.x; i < 4096; i += 256) {
        const int c = counts[i];
        const float frac = (float)c * (1.f / 8192.f);
        d += fabsf(frac - 0.5f);
        z += (c == 0) ? 1.f : 0.f;
        pp += (c == 8192) ? 1.f : 0.f;
    }
    d = block_sum256(d, red);
    z = block_sum256(z, red);
    pp = block_sum256(pp, red);
    if (threadIdx.x == 0) {
        out7[0] = d * (1.f / 4096.f);
        out7[1] = z * (1.f / 4096.f);
        out7[2] = pp * (1.f / 4096.f);
        out7[3] = stats[5] * (1.f / 131072.f);
        out7[4] = sqrtf(stats[0] / stats[1]);
        out7[5] = sqrtf(stats[4] / stats[2]);
        out7[6] = sqrtf(stats[3] / (8192.f * 4096.f));
    }
}

// ---------------------------------------------------------------------------
extern "C" void kernel_launch(void* const* d_in, const int* in_sizes, int n_in,
                              void* d_out, int out_size, void* d_ws, size_t ws_size,
                              hipStream_t stream) {
    const float* x      = (const float*)d_in[0];
    const float* c      = (const float*)d_in[1];
    const float* w_cond = (const float*)d_in[2];
    const float* w_qkv  = (const float*)d_in[3];
    const float* w_attn = (const float*)d_in[4];
    const float* w_mlp1 = (const float*)d_in[5];
    const float* w_mlp2 = (const float*)d_in[6];
    float* out = (float*)d_out;

    char* base = (char*)d_ws;
    size_t off = 0;
    auto alloc = [&](size_t n) { void* r = base + off; off += (n + 255) & ~(size_t)255; return r; };
    float* stats   = (float*)alloc(64);
    int*   counts  = (int*)alloc(4096 * 4);
    float* cm      = (float*)alloc((size_t)8 * 6144 * 4);
    u16*   x_mod   = (u16*)alloc((size_t)8192 * 1024 * 2);
    u16*   kqv     = (u16*)alloc((size_t)8192 * 3072 * 2);
    u16*   vT      = (u16*)alloc((size_t)128 * 64 * 1024 * 2);
    u16*   y       = (u16*)alloc((size_t)8192 * 1024 * 2);
    float* x1      = (float*)alloc((size_t)8192 * 1024 * 4);
    u16*   wt_qkv  = (u16*)alloc((size_t)3072 * 1024 * 2);
    u16*   wt_attn = (u16*)alloc((size_t)1024 * 1024 * 2);
    u16*   wt_mlp1 = (u16*)alloc((size_t)4096 * 1024 * 2);
    u16*   wt_mlp2 = (u16*)alloc((size_t)1024 * 4096 * 2);
    u16*   h_act   = kqv;
    u16*   x_mod2  = x_mod;
    (void)vT; (void)ws_size; (void)n_in; (void)in_sizes; (void)out_size;

    // zero stats + counts + cm (cond accumulates into cm via atomics)
    hipMemsetAsync(d_ws, 0, 256 + 4096 * 4 + 8 * 6144 * 4 + 256, stream);

    dim3 tb(32, 8);
    transpose_cast<<<dim3(3072 / 32, 1024 / 32), tb, 0, stream>>>(w_qkv,  wt_qkv,  1024, 3072);
    transpose_cast<<<dim3(1024 / 32, 1024 / 32), tb, 0, stream>>>(w_attn, wt_attn, 1024, 1024);
    transpose_cast<<<dim3(4096 / 32, 1024 / 32), tb, 0, stream>>>(w_mlp1, wt_mlp1, 1024, 4096);
    transpose_cast<<<dim3(1024 / 32, 4096 / 32), tb, 0, stream>>>(w_mlp2, wt_mlp2, 4096, 1024);

    cond_kernel<<<dim3(24, 32), 256, 0, stream>>>(c, w_cond, cm);

    ln_mod_kernel<<<8192, 256, 0, stream>>>(x, cm, 0, 1024, x_mod);

    // grid: (m_tiles, n_tiles) — blockIdx.x = m_tile for XCD locality
    gemm_epi<0><<<dim3(8192 / 128, 3072 / 128), 256, 0, stream>>>(
        x_mod, wt_qkv, 8192, 3072, 1024, kqv, nullptr, nullptr, nullptr, stats, nullptr);

    vtrans_kernel<<<dim3(32, 2, 128), tb, 0, stream>>>(kqv, vT);

    attn_kernel<<<dim3(16, 128), 256, 0, stream>>>(kqv, vT, y, stats);

    gemm_epi<1><<<dim3(8192 / 128, 1024 / 128), 256, 0, stream>>>(
        y, wt_attn, 8192, 1024, 1024, nullptr, x1, x, cm + 2 * 1024, stats, nullptr);

    ln_mod_kernel<<<8192, 256, 0, stream>>>(x1, cm, 3 * 1024, 4 * 1024, x_mod2);

    gemm_epi<2><<<dim3(8192 / 128, 4096 / 128), 256, 0, stream>>>(
        x_mod2, wt_mlp1, 8192, 4096, 1024, h_act, nullptr, nullptr, nullptr, stats, counts);

    gemm_epi<3><<<dim3(8192 / 128, 1024 / 128), 256, 0, stream>>>(
        h_act, wt_mlp2, 8192, 1024, 4096, nullptr, out, x1, cm + 5 * 1024, stats, nullptr);

    finalize_kernel<<<1, 256, 0, stream>>>(counts, stats, out + (size_t)8192 * 1024);
}